// Round 20
// baseline (55.462 us; speedup 1.0000x reference)
//
#include <hip/hip_runtime.h>
#include <hip/hip_bf16.h>

#define BB 8
#define NN 128
#define ND 64
#define LL 512
#define RD 1024
#define CG 128
#define HID 192

typedef __attribute__((ext_vector_type(8))) short short8;
typedef __attribute__((ext_vector_type(4))) float f32x4;

__device__ __forceinline__ unsigned short f2bf(float x) {
    return __bfloat16_as_ushort(__float2bfloat16(x));
}
__device__ __forceinline__ float bf2f(unsigned short h) {
    unsigned u = ((unsigned)h) << 16;
    return __builtin_bit_cast(float, u);
}
__device__ __forceinline__ float fast_tanh(float x) {
    float e = __expf(2.0f * x);
    return 1.0f - 2.0f * __builtin_amdgcn_rcpf(e + 1.0f);
}
#define MFMA __builtin_amdgcn_mfma_f32_16x16x32_bf16

// ---------------------------------------------------------------------------
// K1, grid 81 x 512:
//  blk 0..63 : h0 via MFMA for (b=blk>>3, ntile=blk&7): writes hA[b][c][n]
//              bf16 (feature-major) + normb for its 16 rows.
//  blk 64..79: WcT[c][k] = bf16((Wr@W1b)[k][c]) via MFMA (R17-verified).
//  blk 80    : vbuf = W2@Wo ; out[b] = cconst ; b1cg = b1 + br@W1b.
// ---------------------------------------------------------------------------
__global__ __launch_bounds__(512, 1) void k1(
    const float* __restrict__ adj, const float* __restrict__ nodes,
    const float* __restrict__ Wn, const float* __restrict__ bn,
    const float* __restrict__ Wr, const float* __restrict__ br,
    const float* __restrict__ W1, const float* __restrict__ b1,
    const float* __restrict__ W2, const float* __restrict__ b2,
    const float* __restrict__ Wo, const float* __restrict__ bo,
    unsigned short* __restrict__ hA, float* __restrict__ normb,
    unsigned short* __restrict__ WcT, float* __restrict__ vbuf,
    float* __restrict__ b1cg, float* __restrict__ out)
{
    __shared__ char pool[53248];
    int t = threadIdx.x, blk = blockIdx.x;
    int w = t >> 6, l = t & 63, lr = l & 15, ks = l >> 4, lk = ks * 8;
    const float* W1b = W1 + CG * HID;

    if (blk < 64) {
        // ---- h0 block ----
        unsigned short* WnTl = (unsigned short*)pool;          // [128][72]
        float* dscr = (float*)(pool + 128 * 72 * 2);           // [16][32]
        int b = blk >> 3, it = blk & 7, i0 = it * 16;
        #pragma unroll
        for (int q = 0; q < 16; ++q) {
            int e = t + 512 * q;
            int c = e & 127, k = e >> 7;
            WnTl[c * 72 + k] = f2bf(Wn[(size_t)k * CG + c]);
        }
        {
            int row = t >> 5, seg = t & 31;
            float4 p = *(const float4*)(adj + ((size_t)b * NN + i0 + row) * NN + seg * 4);
            dscr[row * 32 + seg] = (p.x + p.y) + (p.z + p.w);
        }
        short8 bnod[2];
        #pragma unroll
        for (int kk = 0; kk < 2; ++kk) {
            const float* np = nodes + ((size_t)b * NN + i0 + lr) * ND + kk * 32 + lk;
            float4 q0 = *(const float4*)np;
            float4 q1 = *(const float4*)(np + 4);
            unsigned short u[8];
            u[0]=f2bf(q0.x); u[1]=f2bf(q0.y); u[2]=f2bf(q0.z); u[3]=f2bf(q0.w);
            u[4]=f2bf(q1.x); u[5]=f2bf(q1.y); u[6]=f2bf(q1.z); u[7]=f2bf(q1.w);
            bnod[kk] = *(const short8*)u;
        }
        __syncthreads();
        if (t < 16) {
            float d = 0.f;
            #pragma unroll
            for (int s2 = 0; s2 < 32; ++s2) d += dscr[t * 32 + s2];
            normb[b * NN + i0 + t] = rsqrtf(fmaxf(d, 1.f));
        }
        // h0: wave w -> ct = w (16 c-rows)
        f32x4 d = {0.f, 0.f, 0.f, 0.f};
        #pragma unroll
        for (int kk = 0; kk < 2; ++kk) {
            short8 afw = *(const short8*)(WnTl + (w * 16 + lr) * 72 + kk * 32 + lk);
            d = MFMA(afw, bnod[kk], d, 0, 0, 0);
        }
        #pragma unroll
        for (int i = 0; i < 4; ++i) {
            int c = w * 16 + ks * 4 + i;
            hA[(size_t)(b * CG + c) * NN + i0 + lr] = f2bf(d[i] + bn[c]);
        }
        return;
    }
    if (blk < 80) {
        // ---- WcT via MFMA (R17-verified body) ----
        unsigned short (*W1Tw)[136] = (unsigned short(*)[136])pool;  // [192][136]
        int r0 = (blk - 64) * 64;
        #pragma unroll
        for (int q = 0; q < 48; ++q) {
            int e = t + 512 * q;              // 0..24575
            int m = e / HID, c = e % HID;
            W1Tw[c][m] = f2bf(W1[(size_t)(CG + m) * HID + c]);
        }
        int rt = w & 3, jh = w >> 2;
        short8 awr[4];
        #pragma unroll
        for (int kk = 0; kk < 4; ++kk) {
            const float* wp = Wr + (size_t)(r0 + rt * 16 + lr) * CG + kk * 32 + lk;
            float4 q0 = *(const float4*)wp;
            float4 q1 = *(const float4*)(wp + 4);
            unsigned short u[8];
            u[0]=f2bf(q0.x); u[1]=f2bf(q0.y); u[2]=f2bf(q0.z); u[3]=f2bf(q0.w);
            u[4]=f2bf(q1.x); u[5]=f2bf(q1.y); u[6]=f2bf(q1.z); u[7]=f2bf(q1.w);
            awr[kk] = *(const short8*)u;
        }
        __syncthreads();
        #pragma unroll
        for (int jt6 = 0; jt6 < 6; ++jt6) {
            int jt = jh * 6 + jt6;            // 0..11
            f32x4 d = {0.f, 0.f, 0.f, 0.f};
            #pragma unroll
            for (int kk = 0; kk < 4; ++kk) {
                short8 bf = *(const short8*)(&W1Tw[jt * 16 + lr][kk * 32 + lk]);
                d = MFMA(awr[kk], bf, d, 0, 0, 0);
            }
            unsigned short u[4];
            #pragma unroll
            for (int i = 0; i < 4; ++i) u[i] = f2bf(d[i]);
            *(uint2*)(WcT + (size_t)(jt * 16 + lr) * RD + r0 + rt * 16 + ks * 4) = *(uint2*)u;
        }
        return;
    }
    // ---- consts block ----
    if (t < HID) {
        float s = 0.f;
        #pragma unroll 8
        for (int k = 0; k < CG; ++k) s = fmaf(W2[t * CG + k], Wo[k], s);
        vbuf[t] = s;
    }
    if (t < BB) {
        float s = 0.f;
        for (int k = 0; k < CG; ++k) s = fmaf(b2[k], Wo[k], s);
        out[t] = (float)(NN * LL) * s + bo[0];   // cconst base
    }
    if (t >= 192 && t < 384) {
        int j = t - 192;
        float s = b1[j];
        #pragma unroll 8
        for (int m = 0; m < CG; ++m)
            s = fmaf(br[m], W1b[(size_t)m * HID + j], s);
        b1cg[j] = s;
    }
}

// ---------------------------------------------------------------------------
// K_STEP<FIN>, grid 64 x 512: one GNN step for (b=blk>>3, ntile=blk&7).
// mm1: m = adjn@h (adjn rebuilt in regs from adj+normb); mm2: act(m@Wg+bg).
// FIN=0: relu -> hout[b][c][n]. FIN=1: tanh -> hW1 = W1topT@tanh + b1c.
// Same MFMA orientations as the R17-verified monolith.
// ---------------------------------------------------------------------------
template <int FIN>
__global__ __launch_bounds__(512, 1) void k_step(
    const float* __restrict__ adj, const float* __restrict__ normb,
    const float* __restrict__ Wg, const float* __restrict__ bg,
    const float* __restrict__ W1, const float* __restrict__ b1cg,
    const unsigned short* __restrict__ hin, unsigned short* __restrict__ hout,
    unsigned short* __restrict__ hW1b)
{
    __shared__ char pool[FIN ? 131584 : 79360];
    unsigned short (*hTl)[136]  = (unsigned short(*)[136])(pool);            // 34816
    unsigned short (*WgTl)[136] = (unsigned short(*)[136])(pool + 34816);    // 34816
    unsigned short (*mloc)[136] = (unsigned short(*)[136])(pool + 69632);    // 4352
    unsigned short (*thl)[136]  = (unsigned short(*)[136])(pool + 73984);    // 4352
    float* snl  = (float*)(pool + 78336);                                    // 512
    float* sbgl = (float*)(pool + 78848);                                    // 512
    unsigned short (*W1Tl)[136] = (unsigned short(*)[136])(pool + 79360);    // 52224 (FIN)

    int t = threadIdx.x, blk = blockIdx.x;
    int b = blk >> 3, it = blk & 7, i0 = it * 16;
    int w = t >> 6, l = t & 63, lr = l & 15, ks = l >> 4, lk = ks * 8;

    // stage h (bf16 copy, coalesced)
    #pragma unroll
    for (int q = 0; q < 4; ++q) {
        int e8 = t + 512 * q;            // 0..2047 units of 8
        int row = e8 >> 4, n8 = (e8 & 15) * 8;
        *(short8*)(&hTl[row][n8]) =
            *(const short8*)(hin + (size_t)(b * CG + row) * NN + n8);
    }
    // stage WgT
    #pragma unroll
    for (int q = 0; q < 32; ++q) {
        int e = t + 512 * q;
        int c = e & 127, j = e >> 7;
        WgTl[c][j] = f2bf(Wg[(size_t)j * CG + c]);
    }
    if (FIN) {
        #pragma unroll
        for (int q = 0; q < 32; ++q) {
            int e = t + 512 * q;
            int jj = e & 127, k = e >> 7;
            W1Tl[jj][k] = f2bf(W1[(size_t)k * HID + jj]);
        }
        #pragma unroll
        for (int q = 0; q < 16; ++q) {
            int e = t + 512 * q;
            int jj = 128 + (e & 63), k = e >> 6;
            W1Tl[jj][k] = f2bf(W1[(size_t)k * HID + jj]);
        }
    }
    if (t < 128) snl[t] = normb[b * NN + t];
    else if (t < 256) sbgl[t - 128] = bg[t - 128];
    __syncthreads();

    // adjn fragments in regs (needs snl)
    short8 af[4];
    {
        float ni = snl[i0 + lr];
        const float* ar = adj + ((size_t)b * NN + i0 + lr) * NN;
        #pragma unroll
        for (int kk = 0; kk < 4; ++kk) {
            int kb = kk * 32 + lk;
            float4 p0 = *(const float4*)(ar + kb);
            float4 p1 = *(const float4*)(ar + kb + 4);
            unsigned short u[8];
            u[0] = f2bf(p0.x * ni * snl[kb+0]); u[1] = f2bf(p0.y * ni * snl[kb+1]);
            u[2] = f2bf(p0.z * ni * snl[kb+2]); u[3] = f2bf(p0.w * ni * snl[kb+3]);
            u[4] = f2bf(p1.x * ni * snl[kb+4]); u[5] = f2bf(p1.y * ni * snl[kb+5]);
            u[6] = f2bf(p1.z * ni * snl[kb+6]); u[7] = f2bf(p1.w * ni * snl[kb+7]);
            af[kk] = *(const short8*)u;
        }
    }

    // mm1: wave w -> j-tile w
    {
        int jg = w * 16;
        f32x4 d = {0.f, 0.f, 0.f, 0.f};
        #pragma unroll
        for (int kk = 0; kk < 4; ++kk) {
            short8 bf = *(const short8*)(&hTl[jg + lr][kk * 32 + lk]);
            d = MFMA(af[kk], bf, d, 0, 0, 0);
        }
        #pragma unroll
        for (int i = 0; i < 4; ++i)
            mloc[ks * 4 + i][jg + lr] = f2bf(d[i]);
    }
    __syncthreads();

    // mm2: wave w -> c-tile w (full K over j)
    short8 bm[4];
    #pragma unroll
    for (int kk = 0; kk < 4; ++kk)
        bm[kk] = *(const short8*)(&mloc[lr][kk * 32 + lk]);
    if (!FIN) {
        f32x4 acc = {0.f, 0.f, 0.f, 0.f};
        #pragma unroll
        for (int kk = 0; kk < 4; ++kk) {
            short8 wf = *(const short8*)(&WgTl[w * 16 + lr][kk * 32 + lk]);
            acc = MFMA(wf, bm[kk], acc, 0, 0, 0);
        }
        #pragma unroll
        for (int i = 0; i < 4; ++i) {
            int c = w * 16 + ks * 4 + i;
            hout[(size_t)(b * CG + c) * NN + i0 + lr] =
                f2bf(fmaxf(acc[i] + sbgl[c], 0.f));
        }
    } else {
        f32x4 acc = {0.f, 0.f, 0.f, 0.f};
        #pragma unroll
        for (int kk = 0; kk < 4; ++kk) {
            short8 wf = *(const short8*)(&WgTl[w * 16 + lr][kk * 32 + lk]);
            acc = MFMA(bm[kk], wf, acc, 0, 0, 0);
        }
        #pragma unroll
        for (int i = 0; i < 4; ++i)
            thl[ks * 4 + i][w * 16 + lr] = f2bf(fast_tanh(acc[i] + sbgl[w * 16 + lr]));
        __syncthreads();
        // hW1: 12 jjt over 8 waves (q1 loop)
        short8 bh[4];
        #pragma unroll
        for (int kk = 0; kk < 4; ++kk)
            bh[kk] = *(const short8*)(&thl[lr][kk * 32 + lk]);
        #pragma unroll
        for (int q1 = 0; q1 < 2; ++q1) {
            int jjt = w + 8 * q1;
            if (jjt < 12) {
                f32x4 d = {0.f, 0.f, 0.f, 0.f};
                #pragma unroll
                for (int kk = 0; kk < 4; ++kk) {
                    short8 wf = *(const short8*)(&W1Tl[jjt * 16 + lr][kk * 32 + lk]);
                    d = MFMA(wf, bh[kk], d, 0, 0, 0);
                }
                #pragma unroll
                for (int i = 0; i < 4; ++i) {
                    int jj = jjt * 16 + ks * 4 + i;
                    hW1b[(size_t)(b * HID + jj) * NN + i0 + lr] = f2bf(d[i] + b1cg[jj]);
                }
            }
        }
    }
}

// ---------------------------------------------------------------------------
// K_GEMM, grid 256 x 512 (R17-verified, unchanged).
// ---------------------------------------------------------------------------
__global__ __launch_bounds__(512, 4) void k_gemm(
    const float* __restrict__ prot, const unsigned short* __restrict__ WcT,
    const unsigned short* __restrict__ hW1b, const float* __restrict__ vbuf,
    float* __restrict__ out)
{
    __shared__ unsigned short aT[16 * 1032];   // 33024B
    __shared__ unsigned short h1[HID * 136];   // 52224B
    __shared__ float pbuf[2 * 16 * 192];       // 24576B
    __shared__ float sred[8];
    int t = threadIdx.x, blk = blockIdx.x;
    int b = blk >> 5, lc = blk & 31;
    int w = t >> 6, l = t & 63, lr = l & 15, ks = l >> 4, lk = ks * 8;
    int w2 = w >> 2, wj = w & 3;

    #pragma unroll
    for (int q = 0; q < 4; ++q) {
        int e = t + 512 * q;
        int row = e >> 7;
        int c8 = (e & 127) * 8;
        const float* pr = prot + ((size_t)(b * LL + lc * 16 + row)) * RD + c8;
        float4 p0 = *(const float4*)pr;
        float4 p1 = *(const float4*)(pr + 4);
        unsigned short u[8];
        u[0]=f2bf(p0.x); u[1]=f2bf(p0.y); u[2]=f2bf(p0.z); u[3]=f2bf(p0.w);
        u[4]=f2bf(p1.x); u[5]=f2bf(p1.y); u[6]=f2bf(p1.z); u[7]=f2bf(p1.w);
        *(short8*)(aT + row * 1032 + c8) = *(const short8*)u;
    }
    #pragma unroll
    for (int q = 0; q < 6; ++q) {
        int u8 = t + 512 * q;
        int row = u8 >> 4;
        int n8 = (u8 & 15) * 8;
        short8 v = *(const short8*)(hW1b + (size_t)b * HID * NN + row * NN + n8);
        *(short8*)(h1 + row * 136 + n8) = v;
    }
    float v0 = vbuf[wj * 48 + lr];
    float v1 = vbuf[wj * 48 + 16 + lr];
    float v2 = vbuf[wj * 48 + 32 + lr];
    __syncthreads();

    f32x4 a0 = {0.f,0.f,0.f,0.f}, a1 = a0, a2 = a0;
    {
        const unsigned short* ap = aT + lr * 1032 + w2 * 512 + lk;
        const unsigned short* bp = WcT + (size_t)(wj * 48 + lr) * RD + w2 * 512 + lk;
        #pragma unroll 4
        for (int k0 = 0; k0 < 512; k0 += 32) {
            short8 av = *(const short8*)(ap + k0);
            short8 b0 = *(const short8*)(bp + k0);
            short8 b1 = *(const short8*)(bp + 16 * RD + k0);
            short8 b2 = *(const short8*)(bp + 32 * RD + k0);
            a0 = MFMA(av, b0, a0, 0, 0, 0);
            a1 = MFMA(av, b1, a1, 0, 0, 0);
            a2 = MFMA(av, b2, a2, 0, 0, 0);
        }
    }
    #pragma unroll
    for (int i = 0; i < 4; ++i) {
        int r = ks * 4 + i;
        pbuf[(w2 * 16 + r) * 192 + wj * 48 + lr]      = a0[i];
        pbuf[(w2 * 16 + r) * 192 + wj * 48 + 16 + lr] = a1[i];
        pbuf[(w2 * 16 + r) * 192 + wj * 48 + 32 + lr] = a2[i];
    }
    __syncthreads();
    float rw0[4], rw1[4], rw2[4];
    #pragma unroll
    for (int i = 0; i < 4; ++i) {
        int r = ks * 4 + i;
        rw0[i] = pbuf[r * 192 + wj*48 + lr]      + pbuf[(16 + r) * 192 + wj*48 + lr];
        rw1[i] = pbuf[r * 192 + wj*48 + 16 + lr] + pbuf[(16 + r) * 192 + wj*48 + 16 + lr];
        rw2[i] = pbuf[r * 192 + wj*48 + 32 + lr] + pbuf[(16 + r) * 192 + wj*48 + 32 + lr];
    }

    const unsigned short* h0p = h1 + (wj * 48 + lr) * 136 + w2 * 64;
    const unsigned short* h1p = h0p + 16 * 136;
    const unsigned short* h2p = h0p + 32 * 136;
    float s = 0.f;
    #pragma unroll 2
    for (int n0 = 0; n0 < 64; n0 += 4) {
        unsigned short e0[4], e1[4], e2[4];
        *(uint2*)e0 = *(const uint2*)(h0p + n0);
        *(uint2*)e1 = *(const uint2*)(h1p + n0);
        *(uint2*)e2 = *(const uint2*)(h2p + n0);
        #pragma unroll
        for (int q = 0; q < 4; ++q) {
            float hh0 = bf2f(e0[q]), hh1 = bf2f(e1[q]), hh2 = bf2f(e2[q]);
            #pragma unroll
            for (int i = 0; i < 4; ++i) {
                s = fmaf(v0, fmaxf(rw0[i] + hh0, 0.f), s);
                s = fmaf(v1, fmaxf(rw1[i] + hh1, 0.f), s);
                s = fmaf(v2, fmaxf(rw2[i] + hh2, 0.f), s);
            }
        }
    }
    for (int off = 32; off; off >>= 1) s += __shfl_down(s, off);
    if (l == 0) sred[w] = s;
    __syncthreads();
    if (t == 0) {
        float tot = ((sred[0] + sred[1]) + (sred[2] + sred[3]))
                  + ((sred[4] + sred[5]) + (sred[6] + sred[7]));
        atomicAdd(&out[b], tot);
    }
}

extern "C" void kernel_launch(void* const* d_in, const int* in_sizes, int n_in,
                              void* d_out, int out_size, void* d_ws, size_t ws_size,
                              hipStream_t stream)
{
    const float* adj   = (const float*)d_in[0];
    const float* nodes = (const float*)d_in[1];
    const float* prot  = (const float*)d_in[2];
    const float* Wn    = (const float*)d_in[3];
    const float* bn    = (const float*)d_in[4];
    const float* Wg    = (const float*)d_in[5];
    const float* bg    = (const float*)d_in[6];
    const float* Wr    = (const float*)d_in[7];
    const float* br    = (const float*)d_in[8];
    // d_in[9]=Wa, d_in[10]=ba: unused (softmax over size-1 axis == 1)
    const float* W1    = (const float*)d_in[11];
    const float* b1    = (const float*)d_in[12];
    const float* W2    = (const float*)d_in[13];
    const float* b2    = (const float*)d_in[14];
    const float* Wo    = (const float*)d_in[15];
    const float* bo    = (const float*)d_in[16];

    float* ws    = (float*)d_ws;
    float* vbuf  = ws;                       // [192]
    float* b1cg  = ws + 192;                 // [192]
    float* normb = ws + 384;                 // [8][128]
    unsigned short* hA   = (unsigned short*)(ws + 1408);  // [8][128][128] bf16
    unsigned short* hB   = hA + 131072;                   // [8][128][128] bf16
    unsigned short* hW1b = hB + 131072;                   // [8][192][128] bf16
    unsigned short* WcT  = hW1b + 196608;                 // [192][1024] bf16
    float* out   = (float*)d_out;

    hipLaunchKernelGGL(k1, dim3(81), dim3(512), 0, stream,
                       adj, nodes, Wn, bn, Wr, br, W1, b1, W2, b2, Wo, bo,
                       hA, normb, WcT, vbuf, b1cg, out);
    hipLaunchKernelGGL(k_step<0>, dim3(64), dim3(512), 0, stream,
                       adj, normb, Wg, bg, W1, b1cg, hA, hB, hW1b);
    hipLaunchKernelGGL(k_step<0>, dim3(64), dim3(512), 0, stream,
                       adj, normb, Wg, bg, W1, b1cg, hB, hA, hW1b);
    hipLaunchKernelGGL(k_step<1>, dim3(64), dim3(512), 0, stream,
                       adj, normb, Wg, bg, W1, b1cg, hA, hB, hW1b);
    hipLaunchKernelGGL(k_gemm, dim3(256), dim3(512), 0, stream,
                       prot, WcT, hW1b, vbuf, out);
}